// Round 10
// baseline (216.301 us; speedup 1.0000x reference)
//
#include <hip/hip_runtime.h>
#include <math.h>

#define B 8
#define S 1024
#define D 768
#define H 12
#define DH 64
#define M_TOT (B * S)   // 8192

// 0.125 * log2(e): folds softmax scale AND exp->exp2 conversion into Q
#define QSCALE 0.18033688011112042f

typedef short bf16x8 __attribute__((ext_vector_type(8)));
typedef float f32x4 __attribute__((ext_vector_type(4)));
typedef unsigned u32x4 __attribute__((ext_vector_type(4)));

__device__ __forceinline__ unsigned short f2bf(float x) {
    unsigned u = __builtin_bit_cast(unsigned, x);
    u = (u + 0x7FFFu + ((u >> 16) & 1u)) >> 16;   // RNE
    return (unsigned short)u;
}
__device__ __forceinline__ unsigned short f2bf_ru(float x) {
    return (unsigned short)((__builtin_bit_cast(unsigned, x) + 0x8000u) >> 16);
}
__device__ __forceinline__ unsigned pk2bf_ru(float a, float b) {
    unsigned ua = __builtin_bit_cast(unsigned, a) + 0x8000u;
    unsigned ub = __builtin_bit_cast(unsigned, b) + 0x8000u;
    return __builtin_amdgcn_perm(ub, ua, 0x07060302u);  // hi16(b):hi16(a)
}

// async global->LDS, 16B per lane; lds dest = wave-uniform base + lane*16
__device__ __forceinline__ void async16(const unsigned short* g, unsigned short* l) {
    __builtin_amdgcn_global_load_lds((const __attribute__((address_space(1))) void*)g,
                                     (__attribute__((address_space(3))) void*)l, 16, 0, 0);
}

// ---------------------------------------------------------------------------
// Prep: fused input fp32->bf16 convert (blocks 0..6143) and weight
// convert+transpose Wt[n][k] (blocks 6144..6719)
// ---------------------------------------------------------------------------
__global__ __launch_bounds__(256) void prep(const float* __restrict__ inputs,
                                            unsigned short* __restrict__ Abf,
                                            const float* W0, const float* W1,
                                            const float* W2, const float* W3,
                                            unsigned short* T0, unsigned short* T1,
                                            unsigned short* T2, unsigned short* T3) {
    const int bid = blockIdx.x;
    const int t = threadIdx.x;
    if (bid < 6144) {
        const int i = (bid * 256 + t) * 4;
        const float4 v = *(const float4*)&inputs[i];
        ushort4 o;
        o.x = f2bf(v.x); o.y = f2bf(v.y); o.z = f2bf(v.z); o.w = f2bf(v.w);
        *(ushort4*)&Abf[i] = o;
    } else {
        const int id = bid - 6144;
        const int z = id / 144;
        const int rem = id % 144;
        const int kx = rem % 12, ny = rem / 12;
        const float* Wsrc[4] = {W0, W1, W2, W3};
        unsigned short* Tdst[4] = {T0, T1, T2, T3};
        const float* Wm = Wsrc[z];
        unsigned short* Tm = Tdst[z];
        __shared__ float tile[64][65];
        const int r = t >> 4, c4 = (t & 15) * 4;
        const int k0 = kx * 64, n0 = ny * 64;
#pragma unroll
        for (int rr = 0; rr < 4; ++rr) {
            const float4 v = *(const float4*)&Wm[(size_t)(k0 + r + rr * 16) * D + n0 + c4];
            tile[r + rr * 16][c4 + 0] = v.x;
            tile[r + rr * 16][c4 + 1] = v.y;
            tile[r + rr * 16][c4 + 2] = v.z;
            tile[r + rr * 16][c4 + 3] = v.w;
        }
        __syncthreads();
#pragma unroll
        for (int rr = 0; rr < 4; ++rr) {
            const int nr = r + rr * 16;
            ushort4 o;
            o.x = f2bf(tile[c4 + 0][nr]);
            o.y = f2bf(tile[c4 + 1][nr]);
            o.z = f2bf(tile[c4 + 2][nr]);
            o.w = f2bf(tile[c4 + 3][nr]);
            *(ushort4*)&Tm[(size_t)(n0 + nr) * D + k0 + c4] = o;
        }
    }
}

// ---------------------------------------------------------------------------
// Fused QKV GEMM, 3-stage single-barrier pipeline, XOR-swizzled LDS.
// z: 0=Q (prescaled QSCALE), 1=K, 2=V -> Vt [B,H,DH,S] key-permuted.
// z<2 use operand-SWAPPED MFMA (C: row=n, col=m) so in-lane dim = 4 consecutive
// columns -> packed uint2 epilogue stores.
// ---------------------------------------------------------------------------
__global__ __launch_bounds__(256) void gemm_qkv(const unsigned short* __restrict__ A,
                                                const unsigned short* __restrict__ Wtq,
                                                const unsigned short* __restrict__ Wtk,
                                                const unsigned short* __restrict__ Wtv,
                                                const float* __restrict__ bq,
                                                const float* __restrict__ bk,
                                                const float* __restrict__ bv,
                                                unsigned short* __restrict__ Qb,
                                                unsigned short* __restrict__ Kb,
                                                unsigned short* __restrict__ Vtb) {
    __shared__ unsigned short At[3][128 * 32];
    __shared__ unsigned short Bs[3][128 * 32];
    const int z = blockIdx.z;
    const unsigned short* Bt = (z == 0) ? Wtq : (z == 1) ? Wtk : Wtv;
    const float* bias = (z == 0) ? bq : (z == 1) ? bk : bv;
    const float scale = (z == 0) ? QSCALE : 1.0f;

    const int t = threadIdx.x;
    const int w = t >> 6, lane = t & 63;
    const int quad = lane >> 4, l15 = lane & 15;
    const int m0 = blockIdx.x * 128, n0 = blockIdx.y * 128;
    const int wm = (w & 1) * 64, wn = (w >> 1) * 64;
    const int srow = lane >> 2;
    const int scolg = (((lane & 3) ^ ((lane >> 3) & 3))) * 8;   // swizzled stage chunk
    const int fsw = ((quad ^ ((l15 >> 1) & 3)) * 8);            // swizzled frag chunk
    const int NT = D / 32;  // 24

    // lane base pointers for staging (per-iter math = single add of k0)
    const int r0 = (w * 2) * 16 + srow, r1 = r0 + 16;
    const unsigned short* pa0 = &A[(size_t)(m0 + r0) * D + scolg];
    const unsigned short* pa1 = &A[(size_t)(m0 + r1) * D + scolg];
    const unsigned short* pb0 = &Bt[(size_t)(n0 + r0) * D + scolg];
    const unsigned short* pb1 = &Bt[(size_t)(n0 + r1) * D + scolg];

    #define GSTAGE(buf, k0)                                    \
        {                                                      \
            async16(pa0 + (k0), &At[buf][(w * 2) * 512]);      \
            async16(pa1 + (k0), &At[buf][(w * 2 + 1) * 512]);  \
            async16(pb0 + (k0), &Bs[buf][(w * 2) * 512]);      \
            async16(pb1 + (k0), &Bs[buf][(w * 2 + 1) * 512]);  \
        }

    f32x4 acc[4][4];
#pragma unroll
    for (int i = 0; i < 4; ++i)
#pragma unroll
        for (int j = 0; j < 4; ++j) acc[i][j] = (f32x4){0.f, 0.f, 0.f, 0.f};

    GSTAGE(0, 0);
    GSTAGE(1, 32);
    int cur = 0, nxt = 2;
    for (int kt = 0; kt < NT; ++kt) {
        if (kt + 1 < NT) {
            __asm__ volatile("s_waitcnt vmcnt(4)" ::: "memory");   // tile kt landed (this wave)
        } else {
            __asm__ volatile("s_waitcnt vmcnt(0)" ::: "memory");
        }
        __asm__ volatile("s_barrier" ::: "memory");                // kt ready; kt-1 compute done
        if (kt + 2 < NT) {
            GSTAGE(nxt, (kt + 2) * 32);
            nxt = (nxt == 2) ? 0 : nxt + 1;
        }
        const unsigned short* Atc = At[cur];
        const unsigned short* Bsc = Bs[cur];
        cur = (cur == 2) ? 0 : cur + 1;
        bf16x8 af[4], bfr[4];
#pragma unroll
        for (int i = 0; i < 4; ++i)
            af[i] = *(const bf16x8*)&Atc[(wm + i * 16 + l15) * 32 + fsw];
#pragma unroll
        for (int j = 0; j < 4; ++j)
            bfr[j] = *(const bf16x8*)&Bsc[(wn + j * 16 + l15) * 32 + fsw];
        if (z < 2) {
#pragma unroll
            for (int i = 0; i < 4; ++i)
#pragma unroll
                for (int j = 0; j < 4; ++j)
                    acc[i][j] = __builtin_amdgcn_mfma_f32_16x16x32_bf16(bfr[j], af[i], acc[i][j], 0, 0, 0);
        } else {
#pragma unroll
            for (int i = 0; i < 4; ++i)
#pragma unroll
                for (int j = 0; j < 4; ++j)
                    acc[i][j] = __builtin_amdgcn_mfma_f32_16x16x32_bf16(af[i], bfr[j], acc[i][j], 0, 0, 0);
        }
    }
    #undef GSTAGE

    if (z < 2) {
        // swapped C-layout: col(m)=l15, row(n)=quad*4+r -> 4 consecutive n per lane
        unsigned short* C = (z == 0) ? Qb : Kb;
#pragma unroll
        for (int j = 0; j < 4; ++j) {
            const int nb = n0 + wn + j * 16 + quad * 4;
            const float4 bb = *(const float4*)&bias[nb];
#pragma unroll
            for (int i = 0; i < 4; ++i) {
                const int m = m0 + wm + i * 16 + l15;
                uint2 u;
                u.x = pk2bf_ru((acc[i][j][0] + bb.x) * scale, (acc[i][j][1] + bb.y) * scale);
                u.y = pk2bf_ru((acc[i][j][2] + bb.z) * scale, (acc[i][j][3] + bb.w) * scale);
                *(uint2*)&C[(size_t)m * D + nb] = u;
            }
        }
    } else {
        // original layout: col(n)=l15, row(m)=quad*4+r -> 4 consecutive s in Vt
#pragma unroll
        for (int j = 0; j < 4; ++j) {
            const int col = n0 + wn + j * 16 + l15;
            const float bv2 = bias[col];
#pragma unroll
            for (int i = 0; i < 4; ++i) {
                const int row0 = m0 + wm + i * 16 + quad * 4;
                const int h = col >> 6, dh = col & 63;
                const int bb = row0 >> 10, s0 = row0 & 1023;
                // key permutation within 64-block so attn's packed P regs == B-frags
                const int g = (s0 & 63) >> 2;
                const int kap = ((g >> 3) << 5) | ((g & 3) << 3) | (((g >> 2) & 1) << 2);
                const int s0p = (s0 & ~63) | kap;
                uint2 u;
                u.x = pk2bf_ru(acc[i][j][0] + bv2, acc[i][j][1] + bv2);
                u.y = pk2bf_ru(acc[i][j][2] + bv2, acc[i][j][3] + bv2);
                *(uint2*)&Vtb[((size_t)(bb * H + h) * DH + dh) * S + s0p] = u;
            }
        }
    }
}

// ---------------------------------------------------------------------------
// Output projection GEMM: swapped operands, 3-stage pipeline, fp32 out [M,D]
// (epilogue = packed dwordx4 stores along n)
// ---------------------------------------------------------------------------
__global__ __launch_bounds__(256) void gemm_out(const unsigned short* __restrict__ A,
                                                const unsigned short* __restrict__ Bt,
                                                const float* __restrict__ bias,
                                                float* __restrict__ C) {
    __shared__ unsigned short At[3][128 * 32];
    __shared__ unsigned short Bs[3][128 * 32];
    const int t = threadIdx.x;
    const int w = t >> 6, lane = t & 63;
    const int quad = lane >> 4, l15 = lane & 15;
    const int m0 = blockIdx.x * 128, n0 = blockIdx.y * 128;
    const int wm = (w & 1) * 64, wn = (w >> 1) * 64;
    const int srow = lane >> 2;
    const int scolg = (((lane & 3) ^ ((lane >> 3) & 3))) * 8;
    const int fsw = ((quad ^ ((l15 >> 1) & 3)) * 8);
    const int NT = D / 32;

    const int r0 = (w * 2) * 16 + srow, r1 = r0 + 16;
    const unsigned short* pa0 = &A[(size_t)(m0 + r0) * D + scolg];
    const unsigned short* pa1 = &A[(size_t)(m0 + r1) * D + scolg];
    const unsigned short* pb0 = &Bt[(size_t)(n0 + r0) * D + scolg];
    const unsigned short* pb1 = &Bt[(size_t)(n0 + r1) * D + scolg];

    #define GSTAGE(buf, k0)                                    \
        {                                                      \
            async16(pa0 + (k0), &At[buf][(w * 2) * 512]);      \
            async16(pa1 + (k0), &At[buf][(w * 2 + 1) * 512]);  \
            async16(pb0 + (k0), &Bs[buf][(w * 2) * 512]);      \
            async16(pb1 + (k0), &Bs[buf][(w * 2 + 1) * 512]);  \
        }

    f32x4 acc[4][4];
#pragma unroll
    for (int i = 0; i < 4; ++i)
#pragma unroll
        for (int j = 0; j < 4; ++j) acc[i][j] = (f32x4){0.f, 0.f, 0.f, 0.f};

    GSTAGE(0, 0);
    GSTAGE(1, 32);
    int cur = 0, nxt = 2;
    for (int kt = 0; kt < NT; ++kt) {
        if (kt + 1 < NT) {
            __asm__ volatile("s_waitcnt vmcnt(4)" ::: "memory");
        } else {
            __asm__ volatile("s_waitcnt vmcnt(0)" ::: "memory");
        }
        __asm__ volatile("s_barrier" ::: "memory");
        if (kt + 2 < NT) {
            GSTAGE(nxt, (kt + 2) * 32);
            nxt = (nxt == 2) ? 0 : nxt + 1;
        }
        const unsigned short* Atc = At[cur];
        const unsigned short* Bsc = Bs[cur];
        cur = (cur == 2) ? 0 : cur + 1;
        bf16x8 af[4], bfr[4];
#pragma unroll
        for (int i = 0; i < 4; ++i)
            af[i] = *(const bf16x8*)&Atc[(wm + i * 16 + l15) * 32 + fsw];
#pragma unroll
        for (int j = 0; j < 4; ++j)
            bfr[j] = *(const bf16x8*)&Bsc[(wn + j * 16 + l15) * 32 + fsw];
#pragma unroll
        for (int i = 0; i < 4; ++i)
#pragma unroll
            for (int j = 0; j < 4; ++j)
                acc[i][j] = __builtin_amdgcn_mfma_f32_16x16x32_bf16(bfr[j], af[i], acc[i][j], 0, 0, 0);
    }
    #undef GSTAGE

#pragma unroll
    for (int j = 0; j < 4; ++j) {
        const int nb = n0 + wn + j * 16 + quad * 4;
        const float4 bb = *(const float4*)&bias[nb];
#pragma unroll
        for (int i = 0; i < 4; ++i) {
            const int m = m0 + wm + i * 16 + l15;
            float4 o;
            o.x = acc[i][j][0] + bb.x;
            o.y = acc[i][j][1] + bb.y;
            o.z = acc[i][j][2] + bb.z;
            o.w = acc[i][j][3] + bb.w;
            *(float4*)&C[(size_t)m * D + nb] = o;
        }
    }
}

// ---------------------------------------------------------------------------
// MFMA flash attention, S^T/O^T, 128 q/block, fixed-max exp2 softmax,
// register-resident P (Vt key-permuted), 3-stage single-barrier K/V pipeline.
// ---------------------------------------------------------------------------
__global__ __launch_bounds__(256) void attn_mfma(const unsigned short* __restrict__ Qg,
                                                 const unsigned short* __restrict__ Kg,
                                                 const unsigned short* __restrict__ Vtg,
                                                 unsigned short* __restrict__ ATT) {
    __shared__ unsigned short Ks[3][2 * 64 * 32];   // [buf][kc][key][dh32] swizzled
    __shared__ unsigned short Vs[3][2 * 64 * 32];   // [buf][kc][dh][key32] swizzled

    const int t = threadIdx.x;
    const int w = t >> 6, lane = t & 63;
    const int quad = lane >> 4, l15 = lane & 15;
    const int bh = blockIdx.x % (B * H);
    const int q0 = (blockIdx.x / (B * H)) * 128;
    const int b = bh / H, h = bh % H;

    bf16x8 qb[2][2];
#pragma unroll
    for (int qh = 0; qh < 2; ++qh) {
        const size_t qoff = ((size_t)(b * S + q0 + w * 32 + qh * 16 + l15)) * D + h * DH;
        qb[qh][0] = *(const bf16x8*)&Qg[qoff + quad * 8];
        qb[qh][1] = *(const bf16x8*)&Qg[qoff + 32 + quad * 8];
    }

    f32x4 o[2][4];
#pragma unroll
    for (int qh = 0; qh < 2; ++qh)
#pragma unroll
        for (int n = 0; n < 4; ++n) o[qh][n] = (f32x4){0.f, 0.f, 0.f, 0.f};
    float l_acc[2] = {0.f, 0.f};

    const int srow = lane >> 2;
    const int scol = (((lane & 3) ^ ((lane >> 3) & 3))) * 8;
    const int fsw = ((quad ^ ((l15 >> 1) & 3)) * 8);
    const int NT = S / 64;  // 16

    const unsigned short* kbase = Kg + ((size_t)(b * S + w * 16 + srow)) * D + h * DH + scol;
    const unsigned short* vbase = Vtg + ((size_t)(bh * DH + w * 16 + srow)) * S + scol;

    #define STAGE(ktv, bf)                                                       \
        {                                                                        \
            _Pragma("unroll")                                                    \
            for (int kc = 0; kc < 2; ++kc) {                                     \
                async16(kbase + (size_t)(ktv) * 64 * D + kc * 32,                \
                        &Ks[bf][kc * 2048 + w * 512]);                           \
                async16(vbase + (ktv) * 64 + kc * 32,                            \
                        &Vs[bf][kc * 2048 + w * 512]);                           \
            }                                                                    \
        }

    STAGE(0, 0);
    STAGE(1, 1);
    int cur = 0, nxt = 2;
    for (int kt = 0; kt < NT; ++kt) {
        if (kt + 1 < NT) {
            __asm__ volatile("s_waitcnt vmcnt(4)" ::: "memory");  // tile kt landed (this wave)
        } else {
            __asm__ volatile("s_waitcnt vmcnt(0)" ::: "memory");
        }
        __asm__ volatile("s_barrier" ::: "memory");               // kt ready; kt-1 compute done
        if (kt + 2 < NT) {
            STAGE(kt + 2, nxt);
            nxt = (nxt == 2) ? 0 : nxt + 1;
        }
        const int buf = cur;
        cur = (cur == 2) ? 0 : cur + 1;

        // S^T = K Q^T: lane holds S^T[key=n*16+quad*4+r][q(half)=l15]
        f32x4 sc[2][4];
#pragma unroll
        for (int n = 0; n < 4; ++n) {
            const bf16x8 ka0 = *(const bf16x8*)&Ks[buf][0 * 2048 + (n * 16 + l15) * 32 + fsw];
            const bf16x8 ka1 = *(const bf16x8*)&Ks[buf][1 * 2048 + (n * 16 + l15) * 32 + fsw];
#pragma unroll
            for (int qh = 0; qh < 2; ++qh) {
                f32x4 zz = (f32x4){0.f, 0.f, 0.f, 0.f};
                zz = __builtin_amdgcn_mfma_f32_16x16x32_bf16(ka0, qb[qh][0], zz, 0, 0, 0);
                zz = __builtin_amdgcn_mfma_f32_16x16x32_bf16(ka1, qb[qh][1], zz, 0, 0, 0);
                sc[qh][n] = zz;
            }
        }

        // fixed-max softmax numerators: p = exp2(s); pack to PV B-frags.
        bf16x8 pb[2][2];
#pragma unroll
        for (int qh = 0; qh < 2; ++qh) {
            float p[4][4];
            float rs = 0.f;
#pragma unroll
            for (int n = 0; n < 4; ++n) {
#pragma unroll
                for (int r = 0; r < 4; ++r) {
                    p[n][r] = __builtin_amdgcn_exp2f(sc[qh][n][r]);
                    rs += p[n][r];
                }
            }
            l_acc[qh] += rs;
            u32x4 u0, u1;
            u0.x = pk2bf_ru(p[0][0], p[0][1]);
            u0.y = pk2bf_ru(p[0][2], p[0][3]);
            u0.z = pk2bf_ru(p[1][0], p[1][1]);
            u0.w = pk2bf_ru(p[1][2], p[1][3]);
            u1.x = pk2bf_ru(p[2][0], p[2][1]);
            u1.y = pk2bf_ru(p[2][2], p[2][3]);
            u1.z = pk2bf_ru(p[3][0], p[3][1]);
            u1.w = pk2bf_ru(p[3][2], p[3][3]);
            pb[qh][0] = __builtin_bit_cast(bf16x8, u0);   // keys quad*8..+7 (perm order)
            pb[qh][1] = __builtin_bit_cast(bf16x8, u1);   // keys 32+quad*8..+7
        }

        // O^T += V^T P^T (V staged in permuted key order to match)
#pragma unroll
        for (int n = 0; n < 4; ++n) {
            const bf16x8 va0 = *(const bf16x8*)&Vs[buf][0 * 2048 + (n * 16 + l15) * 32 + fsw];
            const bf16x8 va1 = *(const bf16x8*)&Vs[buf][1 * 2048 + (n * 16 + l15) * 32 + fsw];
#pragma unroll
            for (int qh = 0; qh < 2; ++qh) {
                o[qh][n] = __builtin_amdgcn_mfma_f32_16x16x32_bf16(va0, pb[qh][0], o[qh][n], 0, 0, 0);
                o[qh][n] = __builtin_amdgcn_mfma_f32_16x16x32_bf16(va1, pb[qh][1], o[qh][n], 0, 0, 0);
            }
        }
    }
    #undef STAGE

    // final l reduction across the 4 quads sharing q=l15, then normalize
#pragma unroll
    for (int qh = 0; qh < 2; ++qh) {
        float l = l_acc[qh];
        l += __shfl_xor(l, 16, 64);
        l += __shfl_xor(l, 32, 64);
        const float inv = 1.0f / l;
        const size_t row = (size_t)(b * S + q0 + w * 32 + qh * 16 + l15) * D + h * DH;
#pragma unroll
        for (int n = 0; n < 4; ++n) {
            uint2 u;
            u.x = pk2bf_ru(o[qh][n][0] * inv, o[qh][n][1] * inv);
            u.y = pk2bf_ru(o[qh][n][2] * inv, o[qh][n][3] * inv);
            *(uint2*)&ATT[row + n * 16 + quad * 4] = u;
        }
    }
}

extern "C" void kernel_launch(void* const* d_in, const int* in_sizes, int n_in,
                              void* d_out, int out_size, void* d_ws, size_t ws_size,
                              hipStream_t stream) {
    const float* inputs = (const float*)d_in[0];
    const float* Wq = (const float*)d_in[1];
    const float* bq = (const float*)d_in[2];
    const float* Wk = (const float*)d_in[3];
    const float* bk = (const float*)d_in[4];
    const float* Wv = (const float*)d_in[5];
    const float* bv = (const float*)d_in[6];
    const float* Wo = (const float*)d_in[7];
    const float* bo = (const float*)d_in[8];

    const size_t nA = (size_t)M_TOT * D;
    unsigned short* Abf  = (unsigned short*)d_ws;
    unsigned short* Qb   = Abf + nA;
    unsigned short* Kb   = Qb + nA;
    unsigned short* Vtb  = Kb + nA;
    unsigned short* ATTb = Vtb + nA;
    unsigned short* Wtq  = ATTb + nA;
    unsigned short* Wtk  = Wtq + (size_t)D * D;
    unsigned short* Wtv  = Wtk + (size_t)D * D;
    unsigned short* Wto  = Wtv + (size_t)D * D;

    prep<<<6144 + 576, 256, 0, stream>>>(inputs, Abf, Wq, Wk, Wv, Wo, Wtq, Wtk, Wtv, Wto);

    gemm_qkv<<<dim3(M_TOT / 128, D / 128, 3), 256, 0, stream>>>(
        Abf, Wtq, Wtk, Wtv, bq, bk, bv, Qb, Kb, Vtb);

    attn_mfma<<<dim3((S / 128) * B * H), 256, 0, stream>>>(Qb, Kb, Vtb, ATTb);

    gemm_out<<<dim3(M_TOT / 128, D / 128), 256, 0, stream>>>(ATTb, Wto, bo, (float*)d_out);
}